// Round 4
// baseline (245.905 us; speedup 1.0000x reference)
//
#include <hip/hip_runtime.h>

// TensorDense: e3nn CG tensor product, N=20000, MULT_IN=64, MID=16, OUT=64, l<=2.
// R4: 3 blocks/CU via LDS diet (asymmetric 3+2 slot ping-pong, 51.7 KB total,
// 21 rounds), Wt-transposed float4 weight loads in phase 0. Wave tiling as R3:
// wave = 2 w-tiles x 4 of 8 K-chunks; cross-wave K-half reduction via LDS.

typedef __attribute__((ext_vector_type(4))) float f32x4;
typedef __attribute__((ext_vector_type(4))) float f4;
typedef __attribute__((ext_vector_type(2))) float f2;
typedef __attribute__((ext_vector_type(8))) short short8;
typedef unsigned short ushort_t;
typedef unsigned int uint32;

__device__ __forceinline__ uint32 bfb(float x) {
  uint32 u = __float_as_uint(x);
  return (u + 0x7fffu + ((u >> 16) & 1u)) >> 16;  // RNE fp32->bf16 (pack kernel)
}
__device__ __forceinline__ uint32 pack2f(f2 z) {
  uint32 lo = __float_as_uint(z.x) + 0x8000u;
  uint32 hi = __float_as_uint(z.y) + 0x8000u;
  return __builtin_amdgcn_perm(hi, lo, 0x07060302u);
}

#define C2   0.7071067811865476f
#define C3   0.5773502691896258f
#define C5   0.4472135954999579f
#define C6   0.4082482904638631f
#define C23  0.8164965809277260f
#define C10  0.3162277660168379f
#define C210 0.6324555320336759f
#define C310 0.5477225575051661f
#define C14  0.2672612419124244f
#define C214 0.5345224838248488f
#define C314 0.4629100498862757f

// ---------------- W3 pre-pack + W1/W2 transpose ----------------
// blocks 0..119: W3 -> B-frag bf16 (norm folded). block 120: Wt[brn][l][v][u] fp32.
__global__ __launch_bounds__(256) void pack_w3_kernel(
    const float* __restrict__ W30, const float* __restrict__ W31,
    const float* __restrict__ W32, const float* __restrict__ W10,
    const float* __restrict__ W11, const float* __restrict__ W12,
    const float* __restrict__ W20, const float* __restrict__ W21,
    const float* __restrict__ W22, ushort_t* __restrict__ pack,
    float* __restrict__ Wt) {
  int lc = blockIdx.x;
  if (lc == 120) {
    const float* Ws[6] = {W10, W11, W12, W20, W21, W22};
    for (int idx = threadIdx.x; idx < 6144; idx += 256) {
      int u = idx & 63, v = (idx >> 6) & 15, li = idx >> 10;
      Wt[idx] = Ws[li][u * 16 + v];
    }
    return;
  }
  int t = threadIdx.x >> 6;
  int lam = threadIdx.x & 63;
  const float* W;
  int mb;
  float nrm;
  if (lc < 24) {
    W = W30; mb = lc * 32; nrm = 0.036084391824351615f;        // 1/sqrt(768)
  } else if (lc < 72) {
    W = W31; mb = (lc - 24) * 32; nrm = 0.025515518153991442f; // 1/sqrt(1536)
  } else {
    W = W32; mb = (lc - 72) * 32; nrm = 0.025515518153991442f;
  }
  int w = t * 16 + (lam & 15);
  int m0 = mb + (lam >> 4) * 8;
  ushort_t* dst = pack + ((size_t)(lc * 4 + t) * 64 + lam) * 8;
#pragma unroll
  for (int j = 0; j < 8; ++j)
    dst[j] = (ushort_t)bfb(W[(size_t)(m0 + j) * 64 + w] * nrm);
}

// ---------------- z generation ----------------
// b_s: [s][9 jslots][16 v] floats, s-stride 148 (20 mod 32 -> conflict-free bcast)
template <int NK, int JD, class F>
__device__ __forceinline__ void zgenv(const float* bsj, ushort_t* zrow, F f) {
  uint32 zp[NK][8];
#pragma unroll
  for (int oc = 0; oc < 2; ++oc) {
    f2 bb4[JD][4];
#pragma unroll
    for (int j = 0; j < JD; ++j) {
      f4 lo = *(const f4*)(bsj + j * 16 + oc * 8);
      f4 hi = *(const f4*)(bsj + j * 16 + oc * 8 + 4);
      bb4[j][0] = lo.xy; bb4[j][1] = lo.zw;
      bb4[j][2] = hi.xy; bb4[j][3] = hi.zw;
    }
#pragma unroll
    for (int q = 0; q < 4; ++q) {
      f2 bcol[JD], z[NK];
#pragma unroll
      for (int j = 0; j < JD; ++j) bcol[j] = bb4[j][q];
      f(bcol, z);
#pragma unroll
      for (int k = 0; k < NK; ++k) zp[k][oc * 4 + q] = pack2f(z[k]);
    }
  }
#pragma unroll
  for (int k = 0; k < NK; ++k) {
    uint32* d = (uint32*)(zrow + k * (16 * 264));
    *(uint4*)(d) = make_uint4(zp[k][0], zp[k][1], zp[k][2], zp[k][3]);
    *(uint4*)(d + 4) = make_uint4(zp[k][4], zp[k][5], zp[k][6], zp[k][7]);
  }
}

// ---------------- MFMA: NROW slot-rows, wave's 4 K-chunks, 2 w-tiles ----------------
template <int NROW>
__device__ __forceinline__ void mfma2(const ushort_t* zb, const ushort_t* pk,
                                      int pcbase, int h, int wt0, int lane,
                                      f32x4* accA, f32x4* accB) {
  const int srow = lane & 15, quad = lane >> 4;
  const ushort_t* ab = zb + srow * 264 + quad * 8 + h * 128;
  const ushort_t* bb = pk + ((size_t)((pcbase + h * 4) * 4 + wt0) * 64 + lane) * 8;
#pragma unroll
  for (int c = 0; c < 4; ++c) {
    short8 B0 = *(const short8*)(bb + (size_t)c * 2048);
    short8 B1 = *(const short8*)(bb + (size_t)c * 2048 + 512);
#pragma unroll
    for (int rt = 0; rt < NROW; ++rt) {
      short8 A = *(const short8*)(ab + rt * (16 * 264) + c * 32);
      accA[rt] = __builtin_amdgcn_mfma_f32_16x16x32_bf16(A, B0, accA[rt], 0, 0, 0);
      accB[rt] = __builtin_amdgcn_mfma_f32_16x16x32_bf16(A, B1, accB[rt], 0, 0, 0);
    }
  }
}

#define SLOT 4224                 // ushorts per z slot (16 rows x 264)
#define ZBOFF 12672               // bufB offset: 3 slots

// ---------------- main fused kernel ----------------
__global__ __launch_bounds__(256, 3) void tdense_kernel(
    const float* __restrict__ x0, const float* __restrict__ x1,
    const float* __restrict__ x2, const float* __restrict__ Wt,
    const ushort_t* __restrict__ pack, float* __restrict__ out) {
  __shared__ float b_s[2368];                    // 9.25 KB
  __shared__ __align__(16) ushort_t zbuf[21120]; // 42.2 KB: bufA 3 slots + bufB 2

  const int tid = threadIdx.x;
  const int nbase = blockIdx.x * 16;
  const int s = tid >> 4, v = tid & 15;

  // ---- Phase 0: both branch linears; a in registers, b to LDS ----
  const int n = nbase + s;
  const float* px0 = x0 + (size_t)n * 64;
  const float* px1 = x1 + (size_t)n * 192;
  const float* px2 = x2 + (size_t)n * 320;
  const float* wa0p = Wt + (0 * 16 + v) * 64;
  const float* wa1p = Wt + (1 * 16 + v) * 64;
  const float* wa2p = Wt + (2 * 16 + v) * 64;
  const float* wb0p = Wt + (3 * 16 + v) * 64;
  const float* wb1p = Wt + (4 * 16 + v) * 64;
  const float* wb2p = Wt + (5 * 16 + v) * 64;
  float a0 = 0.f, a1x = 0.f, a1y = 0.f, a1z = 0.f;
  float a2[5] = {0.f, 0.f, 0.f, 0.f, 0.f};
  float b0 = 0.f, b1x = 0.f, b1y = 0.f, b1z = 0.f;
  float b2[5] = {0.f, 0.f, 0.f, 0.f, 0.f};
  for (int u4 = 0; u4 < 16; ++u4) {
    f4 xv0 = *(const f4*)(px0 + u4 * 4);
    f4 xa = *(const f4*)(px1 + u4 * 12);
    f4 xb = *(const f4*)(px1 + u4 * 12 + 4);
    f4 xc = *(const f4*)(px1 + u4 * 12 + 8);
    f4 ya = *(const f4*)(px2 + u4 * 20);
    f4 yb = *(const f4*)(px2 + u4 * 20 + 4);
    f4 yc = *(const f4*)(px2 + u4 * 20 + 8);
    f4 yd = *(const f4*)(px2 + u4 * 20 + 12);
    f4 ye = *(const f4*)(px2 + u4 * 20 + 16);
    f4 wA0 = *(const f4*)(wa0p + u4 * 4);
    f4 wA1 = *(const f4*)(wa1p + u4 * 4);
    f4 wA2 = *(const f4*)(wa2p + u4 * 4);
    f4 wB0 = *(const f4*)(wb0p + u4 * 4);
    f4 wB1 = *(const f4*)(wb1p + u4 * 4);
    f4 wB2 = *(const f4*)(wb2p + u4 * 4);
    float x1e[12], x2e[20];
#pragma unroll
    for (int e = 0; e < 4; ++e) { x1e[e] = xa[e]; x1e[4 + e] = xb[e]; x1e[8 + e] = xc[e]; }
#pragma unroll
    for (int e = 0; e < 4; ++e) {
      x2e[e] = ya[e]; x2e[4 + e] = yb[e]; x2e[8 + e] = yc[e];
      x2e[12 + e] = yd[e]; x2e[16 + e] = ye[e];
    }
#pragma unroll
    for (int r = 0; r < 4; ++r) {
      float xx = xv0[r];
      a0 += xx * wA0[r]; b0 += xx * wB0[r];
      float e0 = x1e[r * 3 + 0], e1 = x1e[r * 3 + 1], e2 = x1e[r * 3 + 2];
      a1x += e0 * wA1[r]; a1y += e1 * wA1[r]; a1z += e2 * wA1[r];
      b1x += e0 * wB1[r]; b1y += e1 * wB1[r]; b1z += e2 * wB1[r];
#pragma unroll
      for (int j = 0; j < 5; ++j) {
        float ev = x2e[r * 5 + j];
        a2[j] += ev * wA2[r];
        b2[j] += ev * wB2[r];
      }
    }
  }
  const float inv8 = 0.125f;
  float ar[9];
  ar[0] = a0 * inv8;
  ar[1] = a1x * inv8; ar[2] = a1y * inv8; ar[3] = a1z * inv8;
#pragma unroll
  for (int j = 0; j < 5; ++j) ar[4 + j] = a2[j] * inv8;
  {
    float* bw = b_s + s * 148 + v;
    bw[0] = b0 * inv8;
    bw[16] = b1x * inv8; bw[32] = b1y * inv8; bw[48] = b1z * inv8;
#pragma unroll
    for (int j = 0; j < 5; ++j) bw[64 + j * 16] = b2[j] * inv8;
  }

  const int lane = tid & 63;
  const int wv = tid >> 6;
  const int p2 = (wv & 1) * 2;  // wave's first w-tile
  const int h = wv >> 1;        // K-half

  f32x4 aA0, aB0, aA1[3], aB1[3], aA2[5], aB2[5];
  aA0 = (f32x4)(0.f); aB0 = (f32x4)(0.f);
#pragma unroll
  for (int i = 0; i < 3; ++i) { aA1[i] = (f32x4)(0.f); aB1[i] = (f32x4)(0.f); }
#pragma unroll
  for (int i = 0; i < 5; ++i) { aA2[i] = (f32x4)(0.f); aB2[i] = (f32x4)(0.f); }

  const float* bsl0 = b_s + s * 148;
  const float* bsl1 = bsl0 + 16;
  const float* bsl2 = bsl0 + 64;
  ushort_t* zA = zbuf + s * 264 + v * 16;  // bufA slot0 row for this thread
  ushort_t* zB = zA + ZBOFF;               // bufB slot0
  const ushort_t* ZA = zbuf;
  const ushort_t* ZB = zbuf + ZBOFF;

  // A0: p0 r0 | p4 r0 | p12 r0
  zgenv<1, 1>(bsl0, zA, [&](const f2* b, f2* z) { z[0] = ar[0] * b[0]; });
  zgenv<1, 3>(bsl1, zA + SLOT, [&](const f2* b, f2* z) {
    z[0] = -C3 * (ar[1] * b[0] + ar[2] * b[1] + ar[3] * b[2]);
  });
  zgenv<1, 5>(bsl2, zA + 2 * SLOT, [&](const f2* b, f2* z) {
    z[0] = C5 * (ar[4] * b[0] + ar[5] * b[1] + ar[6] * b[2] + ar[7] * b[3] + ar[8] * b[4]);
  });
  __syncthreads();

  // B0: p1 r0,r1 ; M(A0)
  zgenv<2, 3>(bsl1, zB, [&](const f2* b, f2* z) {
    z[0] = ar[0] * b[0]; z[1] = ar[0] * b[1];
  });
  mfma2<1>(ZA, pack, 0, h, p2, lane, &aA0, &aB0);
  mfma2<1>(ZA + SLOT, pack, 8, h, p2, lane, &aA0, &aB0);
  mfma2<1>(ZA + 2 * SLOT, pack, 16, h, p2, lane, &aA0, &aB0);
  __syncthreads();

  // A1: p1 r2 | p3 r0,r1 ; M(B0)
  zgenv<1, 3>(bsl1, zA, [&](const f2* b, f2* z) { z[0] = ar[0] * b[2]; });
  zgenv<2, 1>(bsl0, zA + SLOT, [&](const f2* b, f2* z) {
    z[0] = ar[1] * b[0]; z[1] = ar[2] * b[0];
  });
  mfma2<2>(ZB, pack, 24, h, p2, lane, aA1, aB1);
  __syncthreads();

  // B1: p3 r2 | p5 r0 ; M(A1)
  zgenv<1, 1>(bsl0, zB, [&](const f2* b, f2* z) { z[0] = ar[3] * b[0]; });
  zgenv<1, 3>(bsl1, zB + SLOT, [&](const f2* b, f2* z) {
    z[0] = C2 * (ar[2] * b[2] - ar[3] * b[1]);
  });
  mfma2<1>(ZA, pack, 24, h, p2, lane, aA1 + 2, aB1 + 2);
  mfma2<2>(ZA + SLOT, pack, 32, h, p2, lane, aA1, aB1);
  __syncthreads();

  // A2: p5 r1,r2 | p7 r0 ; M(B1)
  zgenv<2, 3>(bsl1, zA, [&](const f2* b, f2* z) {
    z[0] = C2 * (ar[3] * b[0] - ar[1] * b[2]);
    z[1] = C2 * (ar[1] * b[1] - ar[2] * b[0]);
  });
  zgenv<1, 5>(bsl2, zA + 2 * SLOT, [&](const f2* b, f2* z) {
    z[0] = -C310 * ar[2] * b[1] + C10 * ar[1] * b[2] - C310 * ar[3] * b[0] + C310 * ar[1] * b[4];
  });
  mfma2<1>(ZB, pack, 32, h, p2, lane, aA1 + 2, aB1 + 2);
  mfma2<1>(ZB + SLOT, pack, 40, h, p2, lane, aA1, aB1);
  __syncthreads();

  // B2: p7 r1,r2 ; M(A2)
  zgenv<2, 5>(bsl2, zB, [&](const f2* b, f2* z) {
    z[0] = -C210 * ar[2] * b[2] - C310 * ar[3] * b[3] - C310 * ar[1] * b[1];
    z[1] = -C310 * ar[2] * b[3] + C10 * ar[3] * b[2] - C310 * ar[1] * b[0] - C310 * ar[3] * b[4];
  });
  mfma2<2>(ZA, pack, 40, h, p2, lane, aA1 + 1, aB1 + 1);
  mfma2<1>(ZA + 2 * SLOT, pack, 48, h, p2, lane, aA1, aB1);
  __syncthreads();

  // A3: p10 r0,r1,r2 ; M(B2)
  zgenv<3, 3>(bsl1, zA, [&](const f2* b, f2* z) {
    z[0] = -C310 * ar[5] * b[1] + C10 * ar[6] * b[0] - C310 * ar[4] * b[2] + C310 * ar[8] * b[0];
    z[1] = -C210 * ar[6] * b[1] - C310 * ar[7] * b[2] - C310 * ar[5] * b[0];
    z[2] = -C310 * ar[7] * b[1] + C10 * ar[6] * b[2] - C310 * ar[4] * b[0] - C310 * ar[8] * b[2];
  });
  mfma2<2>(ZB, pack, 48, h, p2, lane, aA1 + 1, aB1 + 1);
  __syncthreads();

  // B3: p13 r0,r1 ; M(A3)
  zgenv<2, 5>(bsl2, zB, [&](const f2* b, f2* z) {
    z[0] = C10 * (ar[8] * b[3] - ar[7] * b[4] + ar[4] * b[1] - ar[5] * b[0]) +
           C310 * (ar[7] * b[2] - ar[6] * b[3]);
    z[1] = C10 * (ar[5] * b[3] - ar[7] * b[1]) + C210 * (ar[4] * b[4] - ar[8] * b[0]);
  });
  mfma2<3>(ZA, pack, 56, h, p2, lane, aA1, aB1);
  __syncthreads();

  // A4: p13 r2 | p2 r0,r1 ; M(B3)
  zgenv<1, 5>(bsl2, zA, [&](const f2* b, f2* z) {
    z[0] = C10 * (ar[8] * b[1] - ar[5] * b[4] + ar[7] * b[0] - ar[4] * b[3]) +
           C310 * (ar[6] * b[1] - ar[5] * b[2]);
  });
  zgenv<2, 5>(bsl2, zA + SLOT, [&](const f2* b, f2* z) {
    z[0] = ar[0] * b[0]; z[1] = ar[0] * b[1];
  });
  mfma2<2>(ZB, pack, 64, h, p2, lane, aA1, aB1);
  __syncthreads();

  // B4: p2 r2,r3 ; M(A4)
  zgenv<2, 5>(bsl2, zB, [&](const f2* b, f2* z) {
    z[0] = ar[0] * b[2]; z[1] = ar[0] * b[3];
  });
  mfma2<1>(ZA, pack, 64, h, p2, lane, aA1 + 2, aB1 + 2);
  mfma2<2>(ZA + SLOT, pack, 72, h, p2, lane, aA2, aB2);
  __syncthreads();

  // A5: p2 r4 | p6 r0,r1 ; M(B4)
  zgenv<1, 5>(bsl2, zA, [&](const f2* b, f2* z) { z[0] = ar[0] * b[4]; });
  zgenv<2, 3>(bsl1, zA + SLOT, [&](const f2* b, f2* z) {
    z[0] = C2 * (ar[1] * b[2] + ar[3] * b[0]);
    z[1] = C2 * (ar[2] * b[0] + ar[1] * b[1]);
  });
  mfma2<2>(ZB, pack, 72, h, p2, lane, aA2 + 2, aB2 + 2);
  __syncthreads();

  // B5: p6 r2,r3 ; M(A5)
  zgenv<2, 3>(bsl1, zB, [&](const f2* b, f2* z) {
    z[0] = C23 * ar[2] * b[1] - C6 * (ar[1] * b[0] + ar[3] * b[2]);
    z[1] = C2 * (ar[2] * b[2] + ar[3] * b[1]);
  });
  mfma2<1>(ZA, pack, 72, h, p2, lane, aA2 + 4, aB2 + 4);
  mfma2<2>(ZA + SLOT, pack, 80, h, p2, lane, aA2, aB2);
  __syncthreads();

  // A6: p6 r4 | p8 r0,r1 ; M(B5)
  zgenv<1, 3>(bsl1, zA, [&](const f2* b, f2* z) {
    z[0] = C2 * (ar[3] * b[2] - ar[1] * b[0]);
  });
  zgenv<2, 5>(bsl2, zA + SLOT, [&](const f2* b, f2* z) {
    z[0] = C23 * ar[2] * b[4] + C6 * ar[1] * b[1] - C6 * ar[3] * b[3];
    z[1] = C6 * ar[2] * b[3] - C6 * ar[1] * b[0] - C2 * ar[3] * b[2] - C6 * ar[3] * b[4];
  });
  mfma2<2>(ZB, pack, 80, h, p2, lane, aA2 + 2, aB2 + 2);
  __syncthreads();

  // B6: p8 r2,r3 ; M(A6)
  zgenv<2, 5>(bsl2, zB, [&](const f2* b, f2* z) {
    z[0] = C2 * (ar[3] * b[1] - ar[1] * b[3]);
    z[1] = -C6 * ar[2] * b[1] + C2 * ar[1] * b[2] + C6 * ar[3] * b[0] - C6 * ar[1] * b[4];
  });
  mfma2<1>(ZA, pack, 80, h, p2, lane, aA2 + 4, aB2 + 4);
  mfma2<2>(ZA + SLOT, pack, 88, h, p2, lane, aA2, aB2);
  __syncthreads();

  // A7: p8 r4 | p9 r0,r1 ; M(B6)
  zgenv<1, 5>(bsl2, zA, [&](const f2* b, f2* z) {
    z[0] = -C23 * ar[2] * b[0] + C6 * ar[1] * b[3] + C6 * ar[3] * b[1];
  });
  zgenv<2, 1>(bsl0, zA + SLOT, [&](const f2* b, f2* z) {
    z[0] = ar[4] * b[0]; z[1] = ar[5] * b[0];
  });
  mfma2<2>(ZB, pack, 88, h, p2, lane, aA2 + 2, aB2 + 2);
  __syncthreads();

  // B7: p9 r2,r3 ; M(A7)
  zgenv<2, 1>(bsl0, zB, [&](const f2* b, f2* z) {
    z[0] = ar[6] * b[0]; z[1] = ar[7] * b[0];
  });
  mfma2<1>(ZA, pack, 88, h, p2, lane, aA2 + 4, aB2 + 4);
  mfma2<2>(ZA + SLOT, pack, 96, h, p2, lane, aA2, aB2);
  __syncthreads();

  // A8: p9 r4 | p11 r0,r1 ; M(B7)
  zgenv<1, 1>(bsl0, zA, [&](const f2* b, f2* z) { z[0] = ar[8] * b[0]; });
  zgenv<2, 3>(bsl1, zA + SLOT, [&](const f2* b, f2* z) {
    z[0] = -C23 * ar[8] * b[1] - C6 * ar[5] * b[0] + C6 * ar[7] * b[2];
    z[1] = -C6 * ar[7] * b[1] + C6 * ar[4] * b[0] + C2 * ar[6] * b[2] + C6 * ar[8] * b[2];
  });
  mfma2<2>(ZB, pack, 96, h, p2, lane, aA2 + 2, aB2 + 2);
  __syncthreads();

  // B8: p11 r2,r3 ; M(A8)
  zgenv<2, 3>(bsl1, zB, [&](const f2* b, f2* z) {
    z[0] = C2 * (ar[7] * b[0] - ar[5] * b[2]);
    z[1] = C6 * ar[5] * b[1] - C2 * ar[6] * b[0] - C6 * ar[4] * b[2] + C6 * ar[8] * b[0];
  });
  mfma2<1>(ZA, pack, 96, h, p2, lane, aA2 + 4, aB2 + 4);
  mfma2<2>(ZA + SLOT, pack, 104, h, p2, lane, aA2, aB2);
  __syncthreads();

  // A9: p11 r4 | p14 r0,r1 ; M(B8)
  zgenv<1, 3>(bsl1, zA, [&](const f2* b, f2* z) {
    z[0] = C23 * ar[4] * b[1] - C6 * ar[7] * b[0] - C6 * ar[5] * b[2];
  });
  zgenv<2, 5>(bsl2, zA + SLOT, [&](const f2* b, f2* z) {
    z[0] = C214 * (ar[6] * b[0] + ar[4] * b[2]) - C314 * (ar[5] * b[3] + ar[7] * b[1]);
    z[1] = -C14 * (ar[6] * b[1] + ar[5] * b[2]) + C314 * (ar[5] * b[4] + ar[8] * b[1]) -
           C314 * (ar[7] * b[0] + ar[4] * b[3]);
  });
  mfma2<2>(ZB, pack, 104, h, p2, lane, aA2 + 2, aB2 + 2);
  __syncthreads();

  // B9: p14 r2,r3 ; M(A9)
  zgenv<2, 5>(bsl2, zB, [&](const f2* b, f2* z) {
    z[0] = -C214 * ar[6] * b[2] - C14 * (ar[5] * b[1] + ar[7] * b[3]) +
           C214 * (ar[4] * b[0] + ar[8] * b[4]);
    z[1] = -C14 * (ar[6] * b[3] + ar[7] * b[2]) - C314 * (ar[5] * b[0] + ar[4] * b[1]) -
           C314 * (ar[7] * b[4] + ar[8] * b[3]);
  });
  mfma2<1>(ZA, pack, 104, h, p2, lane, aA2 + 4, aB2 + 4);
  mfma2<2>(ZA + SLOT, pack, 112, h, p2, lane, aA2, aB2);
  __syncthreads();

  // A10: p14 r4 ; M(B9)
  zgenv<1, 5>(bsl2, zA, [&](const f2* b, f2* z) {
    z[0] = C214 * (ar[6] * b[4] + ar[8] * b[2]) + C314 * (ar[5] * b[1] - ar[7] * b[3]);
  });
  mfma2<2>(ZB, pack, 112, h, p2, lane, aA2 + 2, aB2 + 2);
  __syncthreads();

  // M(A10)
  mfma2<1>(ZA, pack, 112, h, p2, lane, aA2 + 4, aB2 + 4);
  __syncthreads();  // all zbuf reads done before reduction reuses it

  // ---- Cross-wave K-half reduction via LDS (36.9 KB scratch in zbuf) ----
  float* red = (float*)zbuf;
  const int col = lane & 15, quad = lane >> 4;
  if (h == 0) {
#pragma unroll
    for (int pp = 0; pp < 2; ++pp) {
      int wt = p2 + pp;
      const f32x4* src0 = pp ? &aB0 : &aA0;
      const f32x4* src1 = pp ? aB1 : aA1;
      const f32x4* src2 = pp ? aB2 : aA2;
      *(f4*)(red + (wt * 9 + 0) * 256 + lane * 4) = src0[0];
#pragma unroll
      for (int o = 0; o < 3; ++o)
        *(f4*)(red + (wt * 9 + 1 + o) * 256 + lane * 4) = src1[o];
#pragma unroll
      for (int o = 0; o < 5; ++o)
        *(f4*)(red + (wt * 9 + 4 + o) * 256 + lane * 4) = src2[o];
    }
  }
  __syncthreads();
  if (h == 1) {
    aA0 += *(const f4*)(red + (p2 * 9 + 0) * 256 + lane * 4);
    aB0 += *(const f4*)(red + ((p2 + 1) * 9 + 0) * 256 + lane * 4);
#pragma unroll
    for (int o = 0; o < 3; ++o) {
      aA1[o] += *(const f4*)(red + (p2 * 9 + 1 + o) * 256 + lane * 4);
      aB1[o] += *(const f4*)(red + ((p2 + 1) * 9 + 1 + o) * 256 + lane * 4);
    }
#pragma unroll
    for (int o = 0; o < 5; ++o) {
      aA2[o] += *(const f4*)(red + (p2 * 9 + 4 + o) * 256 + lane * 4);
      aB2[o] += *(const f4*)(red + ((p2 + 1) * 9 + 4 + o) * 256 + lane * 4);
    }
    const int w0 = p2 * 16 + col, w1 = w0 + 16;
#pragma unroll
    for (int r = 0; r < 4; ++r) {
      int so = quad * 4 + r;
      float* row = out + (size_t)(nbase + so) * 576;
      row[w0] = aA0[r];
      row[w1] = aB0[r];
      row[64 + w0 * 3 + 0] = aA1[0][r];
      row[64 + w0 * 3 + 1] = aA1[1][r];
      row[64 + w0 * 3 + 2] = aA1[2][r];
      row[64 + w1 * 3 + 0] = aB1[0][r];
      row[64 + w1 * 3 + 1] = aB1[1][r];
      row[64 + w1 * 3 + 2] = aB1[2][r];
#pragma unroll
      for (int k = 0; k < 5; ++k) {
        row[256 + w0 * 5 + k] = aA2[k][r];
        row[256 + w1 * 5 + k] = aB2[k][r];
      }
    }
  }
}

extern "C" void kernel_launch(void* const* d_in, const int* in_sizes, int n_in,
                              void* d_out, int out_size, void* d_ws, size_t ws_size,
                              hipStream_t stream) {
  const float* x0 = (const float*)d_in[0];
  const float* x1 = (const float*)d_in[1];
  const float* x2 = (const float*)d_in[2];
  const float* W10 = (const float*)d_in[3];
  const float* W20 = (const float*)d_in[4];
  const float* W11 = (const float*)d_in[5];
  const float* W21 = (const float*)d_in[6];
  const float* W12 = (const float*)d_in[7];
  const float* W22 = (const float*)d_in[8];
  const float* W30 = (const float*)d_in[9];
  const float* W31 = (const float*)d_in[10];
  const float* W32 = (const float*)d_in[11];
  ushort_t* pack = (ushort_t*)d_ws;                       // 491,520 B
  float* Wt = (float*)((char*)d_ws + 491520);             // + 24,576 B

  hipLaunchKernelGGL(pack_w3_kernel, dim3(121), dim3(256), 0, stream,
                     W30, W31, W32, W10, W11, W12, W20, W21, W22, pack, Wt);

  int nsamp = in_sizes[0] / 64;  // 20000
  int nblocks = nsamp / 16;      // 1250
  hipLaunchKernelGGL(tdense_kernel, dim3(nblocks), dim3(256), 0, stream,
                     x0, x1, x2, Wt, pack, (float*)d_out);
}